// Round 11
// baseline (2988.386 us; speedup 1.0000x reference)
//
#include <hip/hip_runtime.h>

// SimpleODELSTM: B=4096, T=512, H=64, INPUT=2, NCLS=64.
// R9 (resubmitted unchanged after broker timeout): deeper occupancy packing.
// 1024 blocks x 4 batch rows -> 4 blocks/CU (4 waves/SIMD; VGPR <= 128).
// One valid batch row per lane quad (tile rows {0,4,8,12}); per-lane pointwise
// work halves again; two more resident waves fill the ds_read->MFMA->tanh->
// ds_write stall windows that R4's 2 blocks/CU left exposed (51% VALUBusy,
// 28% MfmaUtil measured).
// Keeps R1's algebraic transpose elimination (4 LDS planes + 4 barriers/step):
//   a_{i+1} = a_i + [dt W1W2] t_i + dt W1 b2
//   Whh h3  = Whh h_new + [dt WhhW2] S + 3dt Whh b2   (gates t+1)
//   Wf  h3  = Wf  h_new + [dt WfW2 ] S + (3dt Wf b2 + bf)   (out_t)

#define TT 512
#define DT 0.33333334f

// ws layout (floats)
#define OFF_M  0        // dt*W1@W2      [64][64]
#define OFF_N  4096     // dt*Whh@W2     [256][64]
#define OFF_P  20480    // dt*Wf@W2      [64][64]
#define OFF_K1 24576    // dt*W1@b2      [64]
#define OFF_CG 24640    // 3dt*Whh@b2    [256]
#define OFF_C2 24896    // 3dt*Wf@b2+bf  [64]

typedef _Float16 half8 __attribute__((ext_vector_type(8)));
typedef float f32x4 __attribute__((ext_vector_type(4)));

__device__ __forceinline__ float fsig(float x) {
  return __builtin_amdgcn_rcpf(1.0f + __expf(-x));
}
__device__ __forceinline__ float ftanh(float x) {
  return 2.0f * __builtin_amdgcn_rcpf(1.0f + __expf(-2.0f * x)) - 1.0f;
}

__global__ void prep(const float* __restrict__ Whh, const float* __restrict__ W1,
                     const float* __restrict__ W2, const float* __restrict__ b2,
                     const float* __restrict__ Wf, const float* __restrict__ bf,
                     float* __restrict__ ws) {
  int id = (int)blockIdx.x * 256 + (int)threadIdx.x;
  if (id < 4096) {                       // M' = dt * W1 @ W2
    int j = id >> 6, k = id & 63;
    float s = 0.f;
    for (int l = 0; l < 64; ++l) s += W1[j * 64 + l] * W2[l * 64 + k];
    ws[OFF_M + id] = DT * s;
  } else if (id < 20480) {               // N' = dt * Whh @ W2
    int e = id - 4096; int gr = e >> 6, k = e & 63;
    float s = 0.f;
    for (int l = 0; l < 64; ++l) s += Whh[gr * 64 + l] * W2[l * 64 + k];
    ws[OFF_N + e] = DT * s;
  } else if (id < 24576) {               // P' = dt * Wf @ W2
    int e = id - 20480; int j = e >> 6, k = e & 63;
    float s = 0.f;
    for (int l = 0; l < 64; ++l) s += Wf[j * 64 + l] * W2[l * 64 + k];
    ws[OFF_P + e] = DT * s;
  } else if (id < 24640) {               // k1 = dt * W1 @ b2
    int j = id - 24576;
    float s = 0.f;
    for (int l = 0; l < 64; ++l) s += W1[j * 64 + l] * b2[l];
    ws[OFF_K1 + j] = DT * s;
  } else if (id < 24896) {               // cg = 3dt * Whh @ b2
    int gr = id - 24640;
    float s = 0.f;
    for (int l = 0; l < 64; ++l) s += Whh[gr * 64 + l] * b2[l];
    ws[OFF_CG + gr] = 3.0f * DT * s;
  } else if (id < 24960) {               // c2 = 3dt * Wf @ b2 + bf
    int j = id - 24896;
    float s = 0.f;
    for (int l = 0; l < 64; ++l) s += Wf[j * 64 + l] * b2[l];
    ws[OFF_C2 + j] = 3.0f * DT * s + bf[j];
  }
}

// A-plane: [16 rows][64 cols] fp16, 8-col chunks XOR-swizzled by (row&7).
__device__ __forceinline__ half8 rdA(const _Float16* plane, int off) {
  return *(const half8*)(plane + off);
}

__global__ void __launch_bounds__(256, 4)
odelstm(const float* __restrict__ X, const float* __restrict__ Wih,
        const float* __restrict__ Whh, const float* __restrict__ bih,
        const float* __restrict__ bhh, const float* __restrict__ W1,
        const float* __restrict__ b1, const float* __restrict__ Wf,
        const float* __restrict__ ws, float* __restrict__ OUT)
{
  // planes (1024 halfs each): H0, H1 (ping-pong h_new), T0, T1, Sp
  __shared__ __align__(16) _Float16 sh[5 * 1024];

  const int tid = (int)threadIdx.x;
  const int w = tid >> 6;
  const int l = tid & 63;
  const int q = l >> 4;
  const int p = l & 15;
  const int j = (w << 4) | p;        // owned output column
  const int row0 = (int)blockIdx.x << 2;   // 4 batch rows per block

  // ---- weight B-fragments (fp16) in registers ----
  half8 Bhh[4][2], Bw1[2], Bm[2], Bn[4][2], Bp[2], Bof[2];
  #pragma unroll
  for (int g = 0; g < 4; ++g) {
    #pragma unroll
    for (int kt = 0; kt < 2; ++kt) {
      const float* s  = Whh + ((g << 6) | j) * 64 + (kt << 5) + (q << 3);
      const float* sn = ws + OFF_N + (((g << 6) | j) << 6) + (kt << 5) + (q << 3);
      half8 v, vn;
      #pragma unroll
      for (int i = 0; i < 8; ++i) { v[i] = (_Float16)s[i]; vn[i] = (_Float16)sn[i]; }
      Bhh[g][kt] = v; Bn[g][kt] = vn;
    }
  }
  #pragma unroll
  for (int kt = 0; kt < 2; ++kt) {
    const float* s1 = W1 + j * 64 + (kt << 5) + (q << 3);
    const float* sm = ws + OFF_M + (j << 6) + (kt << 5) + (q << 3);
    const float* sp = ws + OFF_P + (j << 6) + (kt << 5) + (q << 3);
    const float* sf = Wf + j * 64 + (kt << 5) + (q << 3);
    half8 v1, vm, vp, vf;
    #pragma unroll
    for (int i = 0; i < 8; ++i) {
      v1[i] = (_Float16)s1[i]; vm[i] = (_Float16)sm[i];
      vp[i] = (_Float16)sp[i]; vf[i] = (_Float16)sf[i];
    }
    Bw1[kt] = v1; Bm[kt] = vm; Bp[kt] = vp; Bof[kt] = vf;
  }

  // per-lane constants
  float bias0[4], biasL[4], wx0[4], wx1[4];
  #pragma unroll
  for (int g = 0; g < 4; ++g) {
    int gr = (g << 6) | j;
    bias0[g] = bih[gr] + bhh[gr];
    biasL[g] = bias0[g] + ws[OFF_CG + gr];
    wx0[g] = Wih[gr * 2];
    wx1[g] = Wih[gr * 2 + 1];
  }
  const float b1c = b1[j];
  const float k1c = ws[OFF_K1 + j];
  const float c2c = ws[OFF_C2 + j];

  // loop-invariant LDS address: valid tile row is q*4 (one row per quad)
  const int trow = q << 2;
  const int waddr = trow * 64 + (((j >> 3) ^ (trow & 7)) << 3) + (j & 7);
  const int roff0 = p * 64 + (((q) ^ (p & 7)) << 3);
  const int roff1 = p * 64 + (((4 | q) ^ (p & 7)) << 3);

  // global pointers: lane handles batch row row0 + q
  const int rb = row0 + q;
  const float* xp = X + rb * 2 * TT;         // ch0 at [t], ch1 at [TT + t]
  float* outp = OUT + (rb * TT) * 64 + j;

  // zero all planes once: dead tile rows must stay 0 forever
  for (int i = tid; i < 5 * 1024; i += 256) sh[i] = (_Float16)0.f;

  // prologue: x(0), gates(0) = x Wih + bias (h0 = 0)
  float x0 = xp[0], x1 = xp[TT];

  f32x4 acc[4];
  #pragma unroll
  for (int g = 0; g < 4; ++g) {
    acc[g][0] = bias0[g] + x0 * wx0[g] + x1 * wx1[g];
    acc[g][1] = 0.f; acc[g][2] = 0.f; acc[g][3] = 0.f;
  }

  float c = 0.f;

  __syncthreads();

  for (int t = 0; t < TT; ++t) {
    _Float16* Hpl = sh + ((t & 1) << 10);       // H0 / H1
    _Float16* T0p = sh + 2048;
    _Float16* T1p = sh + 3072;
    _Float16* Spp = sh + 4096;

    // ---- phase 1: LSTM pointwise -> h_new; write H plane ----
    {
      float ig = fsig(acc[0][0]);
      float fg = fsig(acc[1][0]);
      float gg = ftanh(acc[2][0]);
      float og = fsig(acc[3][0]);
      c = fg * c + ig * gg;
      float hv = og * ftanh(c);
      Hpl[waddr] = (_Float16)hv;
    }
    __syncthreads();  // b1

    // ---- phase 2: a0 = W1 h_new + b1 ; prefetch x(t+1) ----
    half8 hf0 = rdA(Hpl, roff0);
    half8 hf1 = rdA(Hpl, roff1);
    f32x4 aa = {b1c, b1c, b1c, b1c};
    aa = __builtin_amdgcn_mfma_f32_16x16x32_f16(hf0, Bw1[0], aa, 0, 0, 0);
    aa = __builtin_amdgcn_mfma_f32_16x16x32_f16(hf1, Bw1[1], aa, 0, 0, 0);

    int tn = (t + 1 < TT) ? t + 1 : t;
    float nx0 = xp[tn], nx1 = xp[TT + tn];

    // ---- phase 3: t0 = tanh(a0); a1 = a0 + M' t0 + k1 ----
    float t0s = ftanh(aa[0]);
    T0p[waddr] = (_Float16)t0s;
    __syncthreads();  // b2
    half8 t0f0 = rdA(T0p, roff0);
    half8 t0f1 = rdA(T0p, roff1);
    f32x4 a1 = {aa[0] + k1c, 0.f, 0.f, 0.f};
    a1 = __builtin_amdgcn_mfma_f32_16x16x32_f16(t0f0, Bm[0], a1, 0, 0, 0);
    a1 = __builtin_amdgcn_mfma_f32_16x16x32_f16(t0f1, Bm[1], a1, 0, 0, 0);

    // ---- phase 4: t1 = tanh(a1); a2 = a1 + M' t1 + k1 ----
    float t1s = ftanh(a1[0]);
    T1p[waddr] = (_Float16)t1s;
    __syncthreads();  // b3
    half8 t1f0 = rdA(T1p, roff0);
    half8 t1f1 = rdA(T1p, roff1);
    f32x4 a2 = {a1[0] + k1c, 0.f, 0.f, 0.f};
    a2 = __builtin_amdgcn_mfma_f32_16x16x32_f16(t1f0, Bm[0], a2, 0, 0, 0);
    a2 = __builtin_amdgcn_mfma_f32_16x16x32_f16(t1f1, Bm[1], a2, 0, 0, 0);

    // ---- phase 5: t2 = tanh(a2); S = t0+t1+t2; write Sp ----
    {
      float Sv = t0s + t1s + ftanh(a2[0]);
      Spp[waddr] = (_Float16)Sv;
    }
    __syncthreads();  // b4

    // ---- phase 6: gates(t+1) = x Wih + biasL + Whh H + N' S ;
    //               out_t = Wf H + P' S + c2 ----
    half8 sf0 = rdA(Spp, roff0);
    half8 sf1 = rdA(Spp, roff1);

    #pragma unroll
    for (int g = 0; g < 4; ++g) {
      acc[g][0] = biasL[g] + nx0 * wx0[g] + nx1 * wx1[g];
      acc[g][1] = 0.f; acc[g][2] = 0.f; acc[g][3] = 0.f;
      acc[g] = __builtin_amdgcn_mfma_f32_16x16x32_f16(hf0, Bhh[g][0], acc[g], 0, 0, 0);
      acc[g] = __builtin_amdgcn_mfma_f32_16x16x32_f16(hf1, Bhh[g][1], acc[g], 0, 0, 0);
      acc[g] = __builtin_amdgcn_mfma_f32_16x16x32_f16(sf0, Bn[g][0],  acc[g], 0, 0, 0);
      acc[g] = __builtin_amdgcn_mfma_f32_16x16x32_f16(sf1, Bn[g][1],  acc[g], 0, 0, 0);
    }

    f32x4 oa = {c2c, 0.f, 0.f, 0.f};
    oa = __builtin_amdgcn_mfma_f32_16x16x32_f16(hf0, Bof[0], oa, 0, 0, 0);
    oa = __builtin_amdgcn_mfma_f32_16x16x32_f16(hf1, Bof[1], oa, 0, 0, 0);
    oa = __builtin_amdgcn_mfma_f32_16x16x32_f16(sf0, Bp[0],  oa, 0, 0, 0);
    oa = __builtin_amdgcn_mfma_f32_16x16x32_f16(sf1, Bp[1],  oa, 0, 0, 0);

    outp[0] = oa[0];
    outp += 64;

    x0 = nx0; x1 = nx1;
  }
}

extern "C" void kernel_launch(void* const* d_in, const int* in_sizes, int n_in,
                              void* d_out, int out_size, void* d_ws, size_t ws_size,
                              hipStream_t stream) {
  const float* X   = (const float*)d_in[0];
  const float* Wih = (const float*)d_in[1];
  const float* Whh = (const float*)d_in[2];
  const float* bih = (const float*)d_in[3];
  const float* bhh = (const float*)d_in[4];
  const float* W1  = (const float*)d_in[5];
  const float* b1  = (const float*)d_in[6];
  const float* W2  = (const float*)d_in[7];
  const float* b2  = (const float*)d_in[8];
  const float* Wf  = (const float*)d_in[9];
  const float* bf  = (const float*)d_in[10];
  float* OUT = (float*)d_out;
  float* ws  = (float*)d_ws;

  hipLaunchKernelGGL(prep, dim3(98), dim3(256), 0, stream,
                     Whh, W1, W2, b2, Wf, bf, ws);

  int B = in_sizes[0] / (2 * TT);   // 4096
  dim3 grid(B / 4), block(256);     // 1024 blocks -> 4 blocks/CU
  hipLaunchKernelGGL(odelstm, grid, block, 0, stream,
                     X, Wih, Whh, bih, bhh, W1, b1, Wf, ws, OUT);
}

// Round 13
// 1416.246 us; speedup vs baseline: 2.1101x; 2.1101x over previous
//
#include <hip/hip_runtime.h>

// SimpleODELSTM: B=4096, T=512, H=64, INPUT=2, NCLS=64.
// R11 (resubmitted unchanged after broker timeout): R9's 4-blocks/CU packing
// with the register budget restored.
// R9 post-mortem: __launch_bounds__(256,4) cut the compiler budget to 64 VGPR
// -> ~96 VGPRs of loop-invariant weight fragments spilled to scratch ->
// 8.58 GB/dispatch HBM fetch (was 9 MB) -> 2566 us. Occupancy itself was fine
// (47%). Fix: keep grid=1024 x 4 rows/block, revert to __launch_bounds__(256,2)
// (measured spill-free at VGPR=116). Residency comes from actual usage:
// 116 VGPR * 4 waves = 464 <= 512/SIMD, LDS 40KB <= 160KB -> 4 blocks/CU.
// Keeps R1's algebraic transpose elimination (4 LDS planes + 4 barriers/step):
//   a_{i+1} = a_i + [dt W1W2] t_i + dt W1 b2
//   Whh h3  = Whh h_new + [dt WhhW2] S + 3dt Whh b2   (gates t+1)
//   Wf  h3  = Wf  h_new + [dt WfW2 ] S + (3dt Wf b2 + bf)   (out_t)

#define TT 512
#define DT 0.33333334f

// ws layout (floats)
#define OFF_M  0        // dt*W1@W2      [64][64]
#define OFF_N  4096     // dt*Whh@W2     [256][64]
#define OFF_P  20480    // dt*Wf@W2      [64][64]
#define OFF_K1 24576    // dt*W1@b2      [64]
#define OFF_CG 24640    // 3dt*Whh@b2    [256]
#define OFF_C2 24896    // 3dt*Wf@b2+bf  [64]

typedef _Float16 half8 __attribute__((ext_vector_type(8)));
typedef float f32x4 __attribute__((ext_vector_type(4)));

__device__ __forceinline__ float fsig(float x) {
  return __builtin_amdgcn_rcpf(1.0f + __expf(-x));
}
__device__ __forceinline__ float ftanh(float x) {
  return 2.0f * __builtin_amdgcn_rcpf(1.0f + __expf(-2.0f * x)) - 1.0f;
}

__global__ void prep(const float* __restrict__ Whh, const float* __restrict__ W1,
                     const float* __restrict__ W2, const float* __restrict__ b2,
                     const float* __restrict__ Wf, const float* __restrict__ bf,
                     float* __restrict__ ws) {
  int id = (int)blockIdx.x * 256 + (int)threadIdx.x;
  if (id < 4096) {                       // M' = dt * W1 @ W2
    int j = id >> 6, k = id & 63;
    float s = 0.f;
    for (int l = 0; l < 64; ++l) s += W1[j * 64 + l] * W2[l * 64 + k];
    ws[OFF_M + id] = DT * s;
  } else if (id < 20480) {               // N' = dt * Whh @ W2
    int e = id - 4096; int gr = e >> 6, k = e & 63;
    float s = 0.f;
    for (int l = 0; l < 64; ++l) s += Whh[gr * 64 + l] * W2[l * 64 + k];
    ws[OFF_N + e] = DT * s;
  } else if (id < 24576) {               // P' = dt * Wf @ W2
    int e = id - 20480; int j = e >> 6, k = e & 63;
    float s = 0.f;
    for (int l = 0; l < 64; ++l) s += Wf[j * 64 + l] * W2[l * 64 + k];
    ws[OFF_P + e] = DT * s;
  } else if (id < 24640) {               // k1 = dt * W1 @ b2
    int j = id - 24576;
    float s = 0.f;
    for (int l = 0; l < 64; ++l) s += W1[j * 64 + l] * b2[l];
    ws[OFF_K1 + j] = DT * s;
  } else if (id < 24896) {               // cg = 3dt * Whh @ b2
    int gr = id - 24640;
    float s = 0.f;
    for (int l = 0; l < 64; ++l) s += Whh[gr * 64 + l] * b2[l];
    ws[OFF_CG + gr] = 3.0f * DT * s;
  } else if (id < 24960) {               // c2 = 3dt * Wf @ b2 + bf
    int j = id - 24896;
    float s = 0.f;
    for (int l = 0; l < 64; ++l) s += Wf[j * 64 + l] * b2[l];
    ws[OFF_C2 + j] = 3.0f * DT * s + bf[j];
  }
}

// A-plane: [16 rows][64 cols] fp16, 8-col chunks XOR-swizzled by (row&7).
__device__ __forceinline__ half8 rdA(const _Float16* plane, int off) {
  return *(const half8*)(plane + off);
}

__global__ void __launch_bounds__(256, 2)
odelstm(const float* __restrict__ X, const float* __restrict__ Wih,
        const float* __restrict__ Whh, const float* __restrict__ bih,
        const float* __restrict__ bhh, const float* __restrict__ W1,
        const float* __restrict__ b1, const float* __restrict__ Wf,
        const float* __restrict__ ws, float* __restrict__ OUT)
{
  // planes (1024 halfs each): H0, H1 (ping-pong h_new), T0, T1, Sp
  __shared__ __align__(16) _Float16 sh[5 * 1024];

  const int tid = (int)threadIdx.x;
  const int w = tid >> 6;
  const int l = tid & 63;
  const int q = l >> 4;
  const int p = l & 15;
  const int j = (w << 4) | p;        // owned output column
  const int row0 = (int)blockIdx.x << 2;   // 4 batch rows per block

  // ---- weight B-fragments (fp16) in registers ----
  half8 Bhh[4][2], Bw1[2], Bm[2], Bn[4][2], Bp[2], Bof[2];
  #pragma unroll
  for (int g = 0; g < 4; ++g) {
    #pragma unroll
    for (int kt = 0; kt < 2; ++kt) {
      const float* s  = Whh + ((g << 6) | j) * 64 + (kt << 5) + (q << 3);
      const float* sn = ws + OFF_N + (((g << 6) | j) << 6) + (kt << 5) + (q << 3);
      half8 v, vn;
      #pragma unroll
      for (int i = 0; i < 8; ++i) { v[i] = (_Float16)s[i]; vn[i] = (_Float16)sn[i]; }
      Bhh[g][kt] = v; Bn[g][kt] = vn;
    }
  }
  #pragma unroll
  for (int kt = 0; kt < 2; ++kt) {
    const float* s1 = W1 + j * 64 + (kt << 5) + (q << 3);
    const float* sm = ws + OFF_M + (j << 6) + (kt << 5) + (q << 3);
    const float* sp = ws + OFF_P + (j << 6) + (kt << 5) + (q << 3);
    const float* sf = Wf + j * 64 + (kt << 5) + (q << 3);
    half8 v1, vm, vp, vf;
    #pragma unroll
    for (int i = 0; i < 8; ++i) {
      v1[i] = (_Float16)s1[i]; vm[i] = (_Float16)sm[i];
      vp[i] = (_Float16)sp[i]; vf[i] = (_Float16)sf[i];
    }
    Bw1[kt] = v1; Bm[kt] = vm; Bp[kt] = vp; Bof[kt] = vf;
  }

  // per-lane constants
  float bias0[4], biasL[4], wx0[4], wx1[4];
  #pragma unroll
  for (int g = 0; g < 4; ++g) {
    int gr = (g << 6) | j;
    bias0[g] = bih[gr] + bhh[gr];
    biasL[g] = bias0[g] + ws[OFF_CG + gr];
    wx0[g] = Wih[gr * 2];
    wx1[g] = Wih[gr * 2 + 1];
  }
  const float b1c = b1[j];
  const float k1c = ws[OFF_K1 + j];
  const float c2c = ws[OFF_C2 + j];

  // loop-invariant LDS address: valid tile row is q*4 (one row per quad)
  const int trow = q << 2;
  const int waddr = trow * 64 + (((j >> 3) ^ (trow & 7)) << 3) + (j & 7);
  const int roff0 = p * 64 + (((q) ^ (p & 7)) << 3);
  const int roff1 = p * 64 + (((4 | q) ^ (p & 7)) << 3);

  // global pointers: lane handles batch row row0 + q
  const int rb = row0 + q;
  const float* xp = X + rb * 2 * TT;         // ch0 at [t], ch1 at [TT + t]
  float* outp = OUT + (rb * TT) * 64 + j;

  // zero all planes once: dead tile rows must stay 0 forever
  for (int i = tid; i < 5 * 1024; i += 256) sh[i] = (_Float16)0.f;

  // prologue: x(0), gates(0) = x Wih + bias (h0 = 0)
  float x0 = xp[0], x1 = xp[TT];

  f32x4 acc[4];
  #pragma unroll
  for (int g = 0; g < 4; ++g) {
    acc[g][0] = bias0[g] + x0 * wx0[g] + x1 * wx1[g];
    acc[g][1] = 0.f; acc[g][2] = 0.f; acc[g][3] = 0.f;
  }

  float c = 0.f;

  __syncthreads();

  for (int t = 0; t < TT; ++t) {
    _Float16* Hpl = sh + ((t & 1) << 10);       // H0 / H1
    _Float16* T0p = sh + 2048;
    _Float16* T1p = sh + 3072;
    _Float16* Spp = sh + 4096;

    // ---- phase 1: LSTM pointwise -> h_new; write H plane ----
    {
      float ig = fsig(acc[0][0]);
      float fg = fsig(acc[1][0]);
      float gg = ftanh(acc[2][0]);
      float og = fsig(acc[3][0]);
      c = fg * c + ig * gg;
      float hv = og * ftanh(c);
      Hpl[waddr] = (_Float16)hv;
    }
    __syncthreads();  // b1

    // ---- phase 2: a0 = W1 h_new + b1 ; prefetch x(t+1) ----
    half8 hf0 = rdA(Hpl, roff0);
    half8 hf1 = rdA(Hpl, roff1);
    f32x4 aa = {b1c, b1c, b1c, b1c};
    aa = __builtin_amdgcn_mfma_f32_16x16x32_f16(hf0, Bw1[0], aa, 0, 0, 0);
    aa = __builtin_amdgcn_mfma_f32_16x16x32_f16(hf1, Bw1[1], aa, 0, 0, 0);

    int tn = (t + 1 < TT) ? t + 1 : t;
    float nx0 = xp[tn], nx1 = xp[TT + tn];

    // ---- phase 3: t0 = tanh(a0); a1 = a0 + M' t0 + k1 ----
    float t0s = ftanh(aa[0]);
    T0p[waddr] = (_Float16)t0s;
    __syncthreads();  // b2
    half8 t0f0 = rdA(T0p, roff0);
    half8 t0f1 = rdA(T0p, roff1);
    f32x4 a1 = {aa[0] + k1c, 0.f, 0.f, 0.f};
    a1 = __builtin_amdgcn_mfma_f32_16x16x32_f16(t0f0, Bm[0], a1, 0, 0, 0);
    a1 = __builtin_amdgcn_mfma_f32_16x16x32_f16(t0f1, Bm[1], a1, 0, 0, 0);

    // ---- phase 4: t1 = tanh(a1); a2 = a1 + M' t1 + k1 ----
    float t1s = ftanh(a1[0]);
    T1p[waddr] = (_Float16)t1s;
    __syncthreads();  // b3
    half8 t1f0 = rdA(T1p, roff0);
    half8 t1f1 = rdA(T1p, roff1);
    f32x4 a2 = {a1[0] + k1c, 0.f, 0.f, 0.f};
    a2 = __builtin_amdgcn_mfma_f32_16x16x32_f16(t1f0, Bm[0], a2, 0, 0, 0);
    a2 = __builtin_amdgcn_mfma_f32_16x16x32_f16(t1f1, Bm[1], a2, 0, 0, 0);

    // ---- phase 5: t2 = tanh(a2); S = t0+t1+t2; write Sp ----
    {
      float Sv = t0s + t1s + ftanh(a2[0]);
      Spp[waddr] = (_Float16)Sv;
    }
    __syncthreads();  // b4

    // ---- phase 6: gates(t+1) = x Wih + biasL + Whh H + N' S ;
    //               out_t = Wf H + P' S + c2 ----
    half8 sf0 = rdA(Spp, roff0);
    half8 sf1 = rdA(Spp, roff1);

    #pragma unroll
    for (int g = 0; g < 4; ++g) {
      acc[g][0] = biasL[g] + nx0 * wx0[g] + nx1 * wx1[g];
      acc[g][1] = 0.f; acc[g][2] = 0.f; acc[g][3] = 0.f;
      acc[g] = __builtin_amdgcn_mfma_f32_16x16x32_f16(hf0, Bhh[g][0], acc[g], 0, 0, 0);
      acc[g] = __builtin_amdgcn_mfma_f32_16x16x32_f16(hf1, Bhh[g][1], acc[g], 0, 0, 0);
      acc[g] = __builtin_amdgcn_mfma_f32_16x16x32_f16(sf0, Bn[g][0],  acc[g], 0, 0, 0);
      acc[g] = __builtin_amdgcn_mfma_f32_16x16x32_f16(sf1, Bn[g][1],  acc[g], 0, 0, 0);
    }

    f32x4 oa = {c2c, 0.f, 0.f, 0.f};
    oa = __builtin_amdgcn_mfma_f32_16x16x32_f16(hf0, Bof[0], oa, 0, 0, 0);
    oa = __builtin_amdgcn_mfma_f32_16x16x32_f16(hf1, Bof[1], oa, 0, 0, 0);
    oa = __builtin_amdgcn_mfma_f32_16x16x32_f16(sf0, Bp[0],  oa, 0, 0, 0);
    oa = __builtin_amdgcn_mfma_f32_16x16x32_f16(sf1, Bp[1],  oa, 0, 0, 0);

    outp[0] = oa[0];
    outp += 64;

    x0 = nx0; x1 = nx1;
  }
}

extern "C" void kernel_launch(void* const* d_in, const int* in_sizes, int n_in,
                              void* d_out, int out_size, void* d_ws, size_t ws_size,
                              hipStream_t stream) {
  const float* X   = (const float*)d_in[0];
  const float* Wih = (const float*)d_in[1];
  const float* Whh = (const float*)d_in[2];
  const float* bih = (const float*)d_in[3];
  const float* bhh = (const float*)d_in[4];
  const float* W1  = (const float*)d_in[5];
  const float* b1  = (const float*)d_in[6];
  const float* W2  = (const float*)d_in[7];
  const float* b2  = (const float*)d_in[8];
  const float* Wf  = (const float*)d_in[9];
  const float* bf  = (const float*)d_in[10];
  float* OUT = (float*)d_out;
  float* ws  = (float*)d_ws;

  hipLaunchKernelGGL(prep, dim3(98), dim3(256), 0, stream,
                     Whh, W1, W2, b2, Wf, bf, ws);

  int B = in_sizes[0] / (2 * TT);   // 4096
  dim3 grid(B / 4), block(256);     // 1024 blocks; residency-by-usage -> 4/CU
  hipLaunchKernelGGL(odelstm, grid, block, 0, stream,
                     X, Wih, Whh, bih, bhh, W1, b1, Wf, ws, OUT);
}